// Round 4
// baseline (367.193 us; speedup 1.0000x reference)
//
#include <hip/hip_runtime.h>
#include <hip/hip_bf16.h>
#include <math.h>

typedef __bf16 bf16x8 __attribute__((ext_vector_type(8)));
typedef __bf16 bf16x4 __attribute__((ext_vector_type(4)));
typedef float f32x4 __attribute__((ext_vector_type(4)));

#define N_TOK 4096
#define EDIM 512
#define NHEAD 8
#define HD 64
#define LDQKV 1536
#define LDCOMB 896
#define NBIN 100
#define SPLITK 4

// ---------------- fp32 -> bf16 convert, 4 arrays fused ----------------
__global__ void cvt4_kernel(const float* __restrict__ s0, __bf16* __restrict__ d0, int n0,
                            const float* __restrict__ s1, __bf16* __restrict__ d1, int n1,
                            const float* __restrict__ s2, __bf16* __restrict__ d2, int n2,
                            const float* __restrict__ s3, __bf16* __restrict__ d3, int n3) {
    int i = blockIdx.x * blockDim.x + threadIdx.x;
    const float* src; __bf16* dst;
    if (i < n0)                { src = s0; dst = d0; }
    else if (i < n0 + n1)      { i -= n0; src = s1; dst = d1; }
    else if (i < n0 + n1 + n2) { i -= n0 + n1; src = s2; dst = d2; }
    else if (i < n0 + n1 + n2 + n3) { i -= n0 + n1 + n2; src = s3; dst = d3; }
    else return;
    const float4 v = ((const float4*)src)[i];
    bf16x4 o;
    o[0] = (__bf16)v.x; o[1] = (__bf16)v.y; o[2] = (__bf16)v.z; o[3] = (__bf16)v.w;
    ((bf16x4*)dst)[i] = o;
}

// ---------------- generic NT bf16 MFMA GEMM: C = A * B^T + bias ----------------
template<int OUT_MODE>
__global__ __launch_bounds__(256) void gemm_nt(const __bf16* __restrict__ A, int lda,
                                               const __bf16* __restrict__ B, int ldb,
                                               const float* __restrict__ bias,
                                               void* __restrict__ C, int ldc,
                                               int K) {
    __shared__ __attribute__((aligned(16))) __bf16 As[128][40];
    __shared__ __attribute__((aligned(16))) __bf16 Bs[128][40];
    const int tid = threadIdx.x;
    const int wave = tid >> 6, lane = tid & 63;
    const int wm = (wave >> 1) * 64, wn = (wave & 1) * 64;
    const int bm = blockIdx.x * 128, bn = blockIdx.y * 128;
    const int lr = lane & 15, lq = lane >> 4;

    f32x4 acc[4][4] = {};

    for (int k0 = 0; k0 < K; k0 += 32) {
        __syncthreads();
        #pragma unroll
        for (int c = tid; c < 512; c += 256) {
            const int row = c >> 2, k8 = (c & 3) * 8;
            *(bf16x8*)&As[row][k8] = *(const bf16x8*)&A[(size_t)(bm + row) * lda + k0 + k8];
            *(bf16x8*)&Bs[row][k8] = *(const bf16x8*)&B[(size_t)(bn + row) * ldb + k0 + k8];
        }
        __syncthreads();
        bf16x8 af[4], bfr[4];
        #pragma unroll
        for (int i = 0; i < 4; i++) {
            af[i]  = *(const bf16x8*)&As[wm + i * 16 + lr][lq * 8];
            bfr[i] = *(const bf16x8*)&Bs[wn + i * 16 + lr][lq * 8];
        }
        #pragma unroll
        for (int i = 0; i < 4; i++)
            #pragma unroll
            for (int j = 0; j < 4; j++)
                acc[i][j] = __builtin_amdgcn_mfma_f32_16x16x32_bf16(af[i], bfr[j], acc[i][j], 0, 0, 0);
    }

    #pragma unroll
    for (int i = 0; i < 4; i++) {
        #pragma unroll
        for (int j = 0; j < 4; j++) {
            const int col = bn + wn + j * 16 + lr;
            const float bv = bias[col];
            #pragma unroll
            for (int r = 0; r < 4; r++) {
                const int row = bm + wm + i * 16 + lq * 4 + r;
                const float v = acc[i][j][r] + bv;
                if (OUT_MODE == 0) ((float*)C)[(size_t)row * ldc + col] = v;
                else               ((__bf16*)C)[(size_t)row * ldc + col] = (__bf16)v;
            }
        }
    }
}

// ---------------- counting sort by step (100 bins), single block ----------------
__global__ __launch_bounds__(1024) void sort_kernel(const int* __restrict__ steps,
                                                    int* __restrict__ perm,
                                                    int* __restrict__ sstep,
                                                    int* __restrict__ bin_start) {
    __shared__ int hist[NBIN];
    __shared__ int offs[NBIN];
    const int tid = threadIdx.x;
    if (tid < NBIN) hist[tid] = 0;
    __syncthreads();
    for (int i = tid; i < N_TOK; i += 1024)
        atomicAdd(&hist[min(max(steps[i], 0), NBIN - 1)], 1);
    __syncthreads();
    if (tid == 0) {
        int acc = 0;
        for (int s = 0; s < NBIN; s++) { offs[s] = acc; acc += hist[s]; }
    }
    __syncthreads();
    if (tid < NBIN) bin_start[tid] = offs[tid];
    __syncthreads();
    for (int i = tid; i < N_TOK; i += 1024) {
        const int s = min(max(steps[i], 0), NBIN - 1);
        const int pos = atomicAdd(&offs[s], 1);
        perm[pos] = i;
        sstep[pos] = s;
    }
}

// ---------------- gather sorted Q (prescaled), K compact, V^T ----------------
__global__ __launch_bounds__(256) void gather_kernel(const __bf16* __restrict__ qkv,
                                                     const int* __restrict__ perm,
                                                     __bf16* __restrict__ qs,
                                                     __bf16* __restrict__ ks,
                                                     __bf16* __restrict__ vt) {
    __shared__ __attribute__((aligned(16))) __bf16 T[64][72];
    __shared__ int pr[64];
    const int h = blockIdx.y;
    const int n0 = blockIdx.x * 64;
    const int tid = threadIdx.x;
    if (tid < 64) pr[tid] = perm[n0 + tid];
    __syncthreads();
    const float SC = 0.125f * 1.44269504f;   // 1/sqrt(64) * log2(e)
    #pragma unroll
    for (int c = tid; c < 512; c += 256) {
        const int r = c >> 3, d8 = (c & 7) * 8;
        const size_t src = (size_t)pr[r] * LDQKV + h * HD + d8;
        bf16x8 q = *(const bf16x8*)&qkv[src];
        #pragma unroll
        for (int j = 0; j < 8; j++) q[j] = (__bf16)((float)q[j] * SC);
        *(bf16x8*)&qs[(size_t)(n0 + r) * EDIM + h * HD + d8] = q;
        *(bf16x8*)&ks[(size_t)(n0 + r) * EDIM + h * HD + d8] =
            *(const bf16x8*)&qkv[src + EDIM];
        *(bf16x8*)&T[r][d8] = *(const bf16x8*)&qkv[src + 2 * EDIM];
    }
    __syncthreads();
    #pragma unroll
    for (int c = tid; c < 512; c += 256) {
        const int d = c & 63, k8 = (c >> 6) * 8;
        bf16x8 v;
        #pragma unroll
        for (int j = 0; j < 8; j++) v[j] = T[k8 + j][d];
        *(bf16x8*)&vt[(size_t)(h * HD + d) * N_TOK + n0 + k8] = v;
    }
}

// ---------------- flash attention: sorted order, split-K, barrier-free ----------------
// grid (64 qtiles, 8 heads, SPLITK chunks); block 256 = 4 waves x 16 queries.
// Fixed-max softmax (scores bounded): p = exp2(s), no running max, no rescale.
// Partial sums po[c][h][q][d] (f32, unnormalized) + pl[c][h][q].
__global__ __launch_bounds__(256) void attn_kernel(const __bf16* __restrict__ qs,
                                                   const __bf16* __restrict__ ks,
                                                   const __bf16* __restrict__ vt,
                                                   const int* __restrict__ sstep,
                                                   const int* __restrict__ bin_start,
                                                   float* __restrict__ po,
                                                   float* __restrict__ pl) {
    __shared__ __attribute__((aligned(16))) __bf16 Ps[64][136];   // wave-private 16-row bands

    const int h = blockIdx.y;
    const int qtile = blockIdx.x;
    const int ck = blockIdx.z;
    const int tid = threadIdx.x, wave = tid >> 6, lane = tid & 63;
    const int lr = lane & 15, lq = lane >> 4;
    const int qbase = qtile * 64 + wave * 16;

    // K range for this block's chunk
    const int kt0 = bin_start[sstep[qtile * 64]] & ~127;
    const int T = (N_TOK - kt0) >> 7;
    const int kta = kt0 + (((T * ck) / SPLITK) << 7);
    const int ktb = kt0 + (((T * (ck + 1)) / SPLITK) << 7);
    // boundary of masked region for the whole block (rows sorted ascending)
    const int bs_blockmax = bin_start[sstep[qtile * 64 + 63]];

    // Q fragments (A-operand), pre-scaled by 1/8*log2(e)
    bf16x8 aq[2];
    {
        const __bf16* qrow = qs + (size_t)(qbase + lr) * EDIM + h * HD;
        aq[0] = *(const bf16x8*)&qrow[lq * 8];
        aq[1] = *(const bf16x8*)&qrow[32 + lq * 8];
    }
    // per-row blocked-prefix bound: key position < bs_r[r]  =>  masked
    int bs_r[4];
    #pragma unroll
    for (int r = 0; r < 4; r++) bs_r[r] = bin_start[sstep[qbase + lq * 4 + r]];

    float l_i[4] = {0.f, 0.f, 0.f, 0.f};
    f32x4 o[4] = {};

    const __bf16* kbase = ks + h * HD;
    const __bf16* vbase = vt + (size_t)h * HD * N_TOK;

    for (int kt = kta; kt < ktb; kt += 128) {
        // S = Q K^T ; K B-fragments loaded directly from global
        f32x4 s[8];
        #pragma unroll
        for (int t = 0; t < 8; t++) {
            const __bf16* krow = kbase + (size_t)(kt + t * 16 + lr) * EDIM + lq * 8;
            bf16x8 b0 = *(const bf16x8*)krow;
            bf16x8 b1 = *(const bf16x8*)(krow + 32);
            f32x4 a = {};
            a = __builtin_amdgcn_mfma_f32_16x16x32_bf16(aq[0], b0, a, 0, 0, 0);
            a = __builtin_amdgcn_mfma_f32_16x16x32_bf16(aq[1], b1, a, 0, 0, 0);
            s[t] = a;
        }
        // position-based mask, only in the boundary region (uniform branch)
        if (kt < bs_blockmax) {
            #pragma unroll
            for (int t = 0; t < 8; t++) {
                const int col = kt + t * 16 + lr;
                #pragma unroll
                for (int r = 0; r < 4; r++)
                    if (col < bs_r[r]) s[t][r] = -1e9f;
            }
        }
        // p = exp2(s); accumulate denominator; P -> LDS (wave-private band)
        #pragma unroll
        for (int t = 0; t < 8; t++) {
            #pragma unroll
            for (int r = 0; r < 4; r++) {
                const float p = exp2f(s[t][r]);
                l_i[r] += p;
                Ps[wave * 16 + lq * 4 + r][t * 16 + lr] = (__bf16)p;
            }
        }
        // O += P V ; V B-fragments loaded directly from global (vt layout)
        #pragma unroll
        for (int ks2 = 0; ks2 < 4; ks2++) {
            bf16x8 ap = *(const bf16x8*)&Ps[wave * 16 + lr][ks2 * 32 + lq * 8];
            const int kcol = kt + ks2 * 32 + lq * 8;
            #pragma unroll
            for (int dt = 0; dt < 4; dt++) {
                bf16x8 bv = *(const bf16x8*)&vbase[(size_t)(dt * 16 + lr) * N_TOK + kcol];
                o[dt] = __builtin_amdgcn_mfma_f32_16x16x32_bf16(ap, bv, o[dt], 0, 0, 0);
            }
        }
    }

    // reduce denominator across the 16 lanes sharing a row group
    #pragma unroll
    for (int r = 0; r < 4; r++) {
        float v = l_i[r];
        v += __shfl_xor(v, 1);
        v += __shfl_xor(v, 2);
        v += __shfl_xor(v, 4);
        v += __shfl_xor(v, 8);
        l_i[r] = v;
    }
    // store partials
    float* pob = po + (((size_t)(ck * NHEAD + h) * N_TOK) + qbase) * HD;
    #pragma unroll
    for (int dt = 0; dt < 4; dt++)
        #pragma unroll
        for (int r = 0; r < 4; r++)
            pob[(lq * 4 + r) * HD + dt * 16 + lr] = o[dt][r];
    if (lr == 0) {
        #pragma unroll
        for (int r = 0; r < 4; r++)
            pl[(size_t)(ck * NHEAD + h) * N_TOK + qbase + lq * 4 + r] = l_i[r];
    }
}

// ---------------- combine split-K partials, normalize, scatter to ctx ----------------
__global__ __launch_bounds__(256) void combine_kernel(const float* __restrict__ po,
                                                      const float* __restrict__ pl,
                                                      const int* __restrict__ perm,
                                                      __bf16* __restrict__ ctx) {
    const int e = blockIdx.x * 256 + threadIdx.x;   // over 4096*512
    const int q = e >> 9;
    const int col = e & 511;
    const int h = col >> 6, d = col & 63;
    float s = 0.f, l = 0.f;
    #pragma unroll
    for (int c = 0; c < SPLITK; c++) {
        s += po[(((size_t)(c * NHEAD + h) * N_TOK) + q) * HD + d];
        l += pl[(size_t)(c * NHEAD + h) * N_TOK + q];
    }
    ctx[(size_t)perm[q] * EDIM + col] = (__bf16)(s / l);
}

// ---------------- embeddings: combined cols [512, 896) ----------------
__global__ void embed_kernel(const int* __restrict__ dmask, const int* __restrict__ steps,
                             const float* __restrict__ status, __bf16* __restrict__ combined) {
    const int n = blockIdx.x;
    const int c = threadIdx.x;               // 0..383
    __bf16 v;
    if (c < 128) {
        v = (__bf16)status[dmask[n] * 128 + c];
    } else {
        const int st = min(max(steps[n], 0), NBIN - 1);
        const int c2 = c - 128;
        const int p = c2 >> 1;
        const float div = expf((float)(2 * p) * (-9.210340371976184f / 256.0f));
        const float ang = (float)st * div;
        v = (__bf16)((c2 & 1) ? cosf(ang) : sinf(ang));
    }
    combined[(size_t)n * LDCOMB + EDIM + c] = v;
}

// ---------------- LayerNorm + ReLU + residual ----------------
__global__ __launch_bounds__(256) void ln_kernel(const float* __restrict__ h,
                                                 const float* __restrict__ x,
                                                 const float* __restrict__ gamma,
                                                 const float* __restrict__ beta,
                                                 float* __restrict__ out) {
    const int row = blockIdx.x * 4 + (threadIdx.x >> 6);
    const int lane = threadIdx.x & 63;
    const float* hr = h + (size_t)row * EDIM;
    float4 v0 = ((const float4*)hr)[lane];
    float4 v1 = ((const float4*)hr)[64 + lane];
    float sum = v0.x + v0.y + v0.z + v0.w + v1.x + v1.y + v1.z + v1.w;
    float sq = v0.x * v0.x + v0.y * v0.y + v0.z * v0.z + v0.w * v0.w +
               v1.x * v1.x + v1.y * v1.y + v1.z * v1.z + v1.w * v1.w;
    #pragma unroll
    for (int m = 1; m < 64; m <<= 1) {
        sum += __shfl_xor(sum, m);
        sq  += __shfl_xor(sq, m);
    }
    const float mean = sum * (1.0f / EDIM);
    const float var = sq * (1.0f / EDIM) - mean * mean;
    const float rstd = rsqrtf(var + 1e-5f);
    const float* xr = x + (size_t)row * EDIM;
    float* orow = out + (size_t)row * EDIM;
    #pragma unroll
    for (int half = 0; half < 2; half++) {
        const float4 v = half ? v1 : v0;
        const int cb = half * 256 + lane * 4;
        float4 res;
        const float* vp = (const float*)&v;
        float tmp[4];
        #pragma unroll
        for (int i = 0; i < 4; i++) {
            const int c = cb + i;
            float t = (vp[i] - mean) * rstd * gamma[c] + beta[c];
            t = fmaxf(t, 0.f);
            tmp[i] = xr[c] + t;
        }
        res.x = tmp[0]; res.y = tmp[1]; res.z = tmp[2]; res.w = tmp[3];
        ((float4*)orow)[cb >> 2] = res;
    }
}

// ---------------- launch ----------------
extern "C" void kernel_launch(void* const* d_in, const int* in_sizes, int n_in,
                              void* d_out, int out_size, void* d_ws, size_t ws_size,
                              hipStream_t stream) {
    const float* x      = (const float*)d_in[0];
    const int*   dmask  = (const int*)d_in[1];
    const int*   steps  = (const int*)d_in[2];
    const float* status = (const float*)d_in[3];
    const float* w_in   = (const float*)d_in[4];
    const float* b_in   = (const float*)d_in[5];
    const float* w_out  = (const float*)d_in[6];
    const float* b_out  = (const float*)d_in[7];
    const float* w_mlp  = (const float*)d_in[8];
    const float* b_mlp  = (const float*)d_in[9];
    const float* gamma  = (const float*)d_in[10];
    const float* beta   = (const float*)d_in[11];
    float* out = (float*)d_out;

    char* ws = (char*)d_ws;
    size_t off = 0;
    auto alloc = [&](size_t bytes) {
        void* p = ws + off;
        off = (off + bytes + 255) & ~(size_t)255;
        return p;
    };
    __bf16* x_bf    = (__bf16*)alloc((size_t)N_TOK * EDIM * 2);   // reused as qs after qkv GEMM
    __bf16* wqkv_bf = (__bf16*)alloc((size_t)3 * EDIM * EDIM * 2);
    __bf16* wout_bf = (__bf16*)alloc((size_t)EDIM * EDIM * 2);
    __bf16* wmlp_bf = (__bf16*)alloc((size_t)EDIM * LDCOMB * 2);
    __bf16* qkv_bf  = (__bf16*)alloc((size_t)N_TOK * LDQKV * 2);
    __bf16* ks_bf   = (__bf16*)alloc((size_t)N_TOK * EDIM * 2);
    __bf16* vt_bf   = (__bf16*)alloc((size_t)EDIM * N_TOK * 2);
    __bf16* ctx_bf  = (__bf16*)alloc((size_t)N_TOK * EDIM * 2);
    __bf16* comb_bf = (__bf16*)alloc((size_t)N_TOK * LDCOMB * 2);
    float*  h_f32   = (float*)alloc((size_t)N_TOK * EDIM * 4);
    int*    perm    = (int*)alloc(N_TOK * 4);
    int*    sstep   = (int*)alloc(N_TOK * 4);
    int*    binst   = (int*)alloc(NBIN * 4);
    float*  po      = (float*)alloc((size_t)SPLITK * NHEAD * N_TOK * HD * 4);
    float*  pl      = (float*)alloc((size_t)SPLITK * NHEAD * N_TOK * 4);
    __bf16* qs_bf   = x_bf;   // alias: x_bf dead after qkv GEMM

    // fused converts
    {
        const int n0 = N_TOK * EDIM / 4;
        const int n1 = 3 * EDIM * EDIM / 4;
        const int n2 = EDIM * EDIM / 4;
        const int n3 = EDIM * LDCOMB / 4;
        const int tot = n0 + n1 + n2 + n3;
        cvt4_kernel<<<(tot + 255) / 256, 256, 0, stream>>>(
            x, x_bf, n0, w_in, wqkv_bf, n1, w_out, wout_bf, n2, w_mlp, wmlp_bf, n3);
    }
    // qkv = x @ w_in^T + b_in
    gemm_nt<1><<<dim3(N_TOK / 128, 3 * EDIM / 128), 256, 0, stream>>>(
        x_bf, EDIM, wqkv_bf, EDIM, b_in, qkv_bf, LDQKV, EDIM);
    // counting sort by step
    sort_kernel<<<1, 1024, 0, stream>>>(steps, perm, sstep, binst);
    // gather sorted Q/K/V^T
    gather_kernel<<<dim3(N_TOK / 64, NHEAD), 256, 0, stream>>>(qkv_bf, perm, qs_bf, ks_bf, vt_bf);
    // attention (split-K, barrier-free)
    attn_kernel<<<dim3(N_TOK / 64, NHEAD, SPLITK), 256, 0, stream>>>(
        qs_bf, ks_bf, vt_bf, sstep, binst, po, pl);
    // combine partials -> ctx (original token order)
    combine_kernel<<<(N_TOK * EDIM) / 256, 256, 0, stream>>>(po, pl, perm, ctx_bf);
    // out proj
    gemm_nt<1><<<dim3(N_TOK / 128, EDIM / 128), 256, 0, stream>>>(
        ctx_bf, EDIM, wout_bf, EDIM, b_out, comb_bf, LDCOMB, EDIM);
    // embeddings
    embed_kernel<<<N_TOK, 384, 0, stream>>>(dmask, steps, status, comb_bf);
    // mlp
    gemm_nt<0><<<dim3(N_TOK / 128, EDIM / 128), 256, 0, stream>>>(
        comb_bf, LDCOMB, wmlp_bf, LDCOMB, b_mlp, h_f32, EDIM, LDCOMB);
    // LN + ReLU + residual
    ln_kernel<<<N_TOK / 4, 256, 0, stream>>>(h_f32, x, gamma, beta, out);
}

// Round 5
// 244.982 us; speedup vs baseline: 1.4989x; 1.4989x over previous
//
#include <hip/hip_runtime.h>
#include <hip/hip_bf16.h>
#include <math.h>

typedef __bf16 bf16x8 __attribute__((ext_vector_type(8)));
typedef __bf16 bf16x4 __attribute__((ext_vector_type(4)));
typedef float f32x4 __attribute__((ext_vector_type(4)));

#define N_TOK 4096
#define EDIM 512
#define NHEAD 8
#define HD 64
#define LDQKV 1536
#define LDCOMB 896
#define NBIN 100
#define SPLITK 4
#define BK 64

// ---------------- fp32 -> bf16 convert, 4 arrays fused ----------------
__global__ void cvt4_kernel(const float* __restrict__ s0, __bf16* __restrict__ d0, int n0,
                            const float* __restrict__ s1, __bf16* __restrict__ d1, int n1,
                            const float* __restrict__ s2, __bf16* __restrict__ d2, int n2,
                            const float* __restrict__ s3, __bf16* __restrict__ d3, int n3) {
    int i = blockIdx.x * blockDim.x + threadIdx.x;
    const float* src; __bf16* dst;
    if (i < n0)                { src = s0; dst = d0; }
    else if (i < n0 + n1)      { i -= n0; src = s1; dst = d1; }
    else if (i < n0 + n1 + n2) { i -= n0 + n1; src = s2; dst = d2; }
    else if (i < n0 + n1 + n2 + n3) { i -= n0 + n1 + n2; src = s3; dst = d3; }
    else return;
    const float4 v = ((const float4*)src)[i];
    bf16x4 o;
    o[0] = (__bf16)v.x; o[1] = (__bf16)v.y; o[2] = (__bf16)v.z; o[3] = (__bf16)v.w;
    ((bf16x4*)dst)[i] = o;
}

// ---------------- generic NT bf16 MFMA GEMM: C = A * B^T + bias ----------------
template<int OUT_MODE>
__global__ __launch_bounds__(256) void gemm_nt(const __bf16* __restrict__ A, int lda,
                                               const __bf16* __restrict__ B, int ldb,
                                               const float* __restrict__ bias,
                                               void* __restrict__ C, int ldc,
                                               int K) {
    __shared__ __attribute__((aligned(16))) __bf16 As[128][40];
    __shared__ __attribute__((aligned(16))) __bf16 Bs[128][40];
    const int tid = threadIdx.x;
    const int wave = tid >> 6, lane = tid & 63;
    const int wm = (wave >> 1) * 64, wn = (wave & 1) * 64;
    const int bm = blockIdx.x * 128, bn = blockIdx.y * 128;
    const int lr = lane & 15, lq = lane >> 4;

    f32x4 acc[4][4] = {};

    for (int k0 = 0; k0 < K; k0 += 32) {
        __syncthreads();
        #pragma unroll
        for (int c = tid; c < 512; c += 256) {
            const int row = c >> 2, k8 = (c & 3) * 8;
            *(bf16x8*)&As[row][k8] = *(const bf16x8*)&A[(size_t)(bm + row) * lda + k0 + k8];
            *(bf16x8*)&Bs[row][k8] = *(const bf16x8*)&B[(size_t)(bn + row) * ldb + k0 + k8];
        }
        __syncthreads();
        bf16x8 af[4], bfr[4];
        #pragma unroll
        for (int i = 0; i < 4; i++) {
            af[i]  = *(const bf16x8*)&As[wm + i * 16 + lr][lq * 8];
            bfr[i] = *(const bf16x8*)&Bs[wn + i * 16 + lr][lq * 8];
        }
        #pragma unroll
        for (int i = 0; i < 4; i++)
            #pragma unroll
            for (int j = 0; j < 4; j++)
                acc[i][j] = __builtin_amdgcn_mfma_f32_16x16x32_bf16(af[i], bfr[j], acc[i][j], 0, 0, 0);
    }

    #pragma unroll
    for (int i = 0; i < 4; i++) {
        #pragma unroll
        for (int j = 0; j < 4; j++) {
            const int col = bn + wn + j * 16 + lr;
            const float bv = bias[col];
            #pragma unroll
            for (int r = 0; r < 4; r++) {
                const int row = bm + wm + i * 16 + lq * 4 + r;
                const float v = acc[i][j][r] + bv;
                if (OUT_MODE == 0) ((float*)C)[(size_t)row * ldc + col] = v;
                else               ((__bf16*)C)[(size_t)row * ldc + col] = (__bf16)v;
            }
        }
    }
}

// ---------------- counting sort by step (100 bins), single block ----------------
__global__ __launch_bounds__(1024) void sort_kernel(const int* __restrict__ steps,
                                                    int* __restrict__ perm,
                                                    int* __restrict__ sstep,
                                                    int* __restrict__ bin_start) {
    __shared__ int hist[NBIN];
    __shared__ int offs[NBIN];
    const int tid = threadIdx.x;
    if (tid < NBIN) hist[tid] = 0;
    __syncthreads();
    for (int i = tid; i < N_TOK; i += 1024)
        atomicAdd(&hist[min(max(steps[i], 0), NBIN - 1)], 1);
    __syncthreads();
    if (tid == 0) {
        int acc = 0;
        for (int s = 0; s < NBIN; s++) { offs[s] = acc; acc += hist[s]; }
    }
    __syncthreads();
    if (tid < NBIN) bin_start[tid] = offs[tid];
    __syncthreads();
    for (int i = tid; i < N_TOK; i += 1024) {
        const int s = min(max(steps[i], 0), NBIN - 1);
        const int pos = atomicAdd(&offs[s], 1);
        perm[pos] = i;
        sstep[pos] = s;
    }
}

// ---------------- gather sorted Q (prescaled), K compact, V^T ----------------
__global__ __launch_bounds__(256) void gather_kernel(const __bf16* __restrict__ qkv,
                                                     const int* __restrict__ perm,
                                                     __bf16* __restrict__ qs,
                                                     __bf16* __restrict__ ks,
                                                     __bf16* __restrict__ vt) {
    __shared__ __attribute__((aligned(16))) __bf16 T[64][72];
    __shared__ int pr[64];
    const int h = blockIdx.y;
    const int n0 = blockIdx.x * 64;
    const int tid = threadIdx.x;
    if (tid < 64) pr[tid] = perm[n0 + tid];
    __syncthreads();
    const float SC = 0.125f * 1.44269504f;   // 1/sqrt(64) * log2(e)
    #pragma unroll
    for (int c = tid; c < 512; c += 256) {
        const int r = c >> 3, d8 = (c & 7) * 8;
        const size_t src = (size_t)pr[r] * LDQKV + h * HD + d8;
        bf16x8 q = *(const bf16x8*)&qkv[src];
        #pragma unroll
        for (int j = 0; j < 8; j++) q[j] = (__bf16)((float)q[j] * SC);
        *(bf16x8*)&qs[(size_t)(n0 + r) * EDIM + h * HD + d8] = q;
        *(bf16x8*)&ks[(size_t)(n0 + r) * EDIM + h * HD + d8] =
            *(const bf16x8*)&qkv[src + EDIM];
        *(bf16x8*)&T[r][d8] = *(const bf16x8*)&qkv[src + 2 * EDIM];
    }
    __syncthreads();
    #pragma unroll
    for (int c = tid; c < 512; c += 256) {
        const int d = c & 63, k8 = (c >> 6) * 8;
        bf16x8 v;
        #pragma unroll
        for (int j = 0; j < 8; j++) v[j] = T[k8 + j][d];
        *(bf16x8*)&vt[(size_t)(h * HD + d) * N_TOK + n0 + k8] = v;
    }
}

// ---------------- flash attention: sorted order, split-K, LDS-staged BK=64 ----------------
// grid (64 qtiles, 8 heads, SPLITK); block 256 = 4 waves x 16 queries.
// Fixed-max softmax (scores bounded, verified R4): p = exp2(s); combine sums partials.
__global__ __launch_bounds__(256) void attn_kernel(const __bf16* __restrict__ qs,
                                                   const __bf16* __restrict__ ks,
                                                   const __bf16* __restrict__ vt,
                                                   const int* __restrict__ sstep,
                                                   const int* __restrict__ bin_start,
                                                   float* __restrict__ po,
                                                   float* __restrict__ pl) {
    __shared__ __attribute__((aligned(16))) __bf16 Ks[BK][72];   // [key][d]
    __shared__ __attribute__((aligned(16))) __bf16 Vs[64][BK + 8]; // [d][key]
    __shared__ __attribute__((aligned(16))) __bf16 Ps[64][BK + 8]; // [q][key] wave-private bands

    const int h = blockIdx.y;
    const int qtile = blockIdx.x;
    const int ck = blockIdx.z;
    const int tid = threadIdx.x, wave = tid >> 6, lane = tid & 63;
    const int lr = lane & 15, lq = lane >> 4;
    const int qbase = qtile * 64 + wave * 16;

    // K range for this chunk
    const int kt0 = bin_start[sstep[qtile * 64]] & ~(BK - 1);
    const int nt = (N_TOK - kt0) / BK;
    const int kta = kt0 + ((nt * ck) / SPLITK) * BK;
    const int ktb = kt0 + ((nt * (ck + 1)) / SPLITK) * BK;
    const int bs_blockmax = bin_start[sstep[qtile * 64 + 63]];

    bf16x8 aq[2];
    {
        const __bf16* qrow = qs + (size_t)(qbase + lr) * EDIM + h * HD;
        aq[0] = *(const bf16x8*)&qrow[lq * 8];
        aq[1] = *(const bf16x8*)&qrow[32 + lq * 8];
    }
    int bs_r[4];
    #pragma unroll
    for (int r = 0; r < 4; r++) bs_r[r] = bin_start[sstep[qbase + lq * 4 + r]];

    float l_i[4] = {0.f, 0.f, 0.f, 0.f};
    f32x4 o[4] = {};

    const __bf16* kbase = ks + h * HD;
    const __bf16* vbase = vt + (size_t)h * HD * N_TOK;

    for (int kt = kta; kt < ktb; kt += BK) {
        __syncthreads();
        // stage K tile [64][64]
        #pragma unroll
        for (int c = tid; c < 512; c += 256) {
            const int row = c >> 3, k8 = (c & 7) * 8;
            *(bf16x8*)&Ks[row][k8] = *(const bf16x8*)&kbase[(size_t)(kt + row) * EDIM + k8];
        }
        // stage V^T tile [64][64]
        #pragma unroll
        for (int c = tid; c < 512; c += 256) {
            const int d = c >> 3, k8 = (c & 7) * 8;
            *(bf16x8*)&Vs[d][k8] = *(const bf16x8*)&vbase[(size_t)d * N_TOK + kt + k8];
        }
        __syncthreads();

        // S = Q K^T  (4 col-blocks of 16 keys)
        f32x4 s[4];
        #pragma unroll
        for (int t = 0; t < 4; t++) {
            bf16x8 b0 = *(const bf16x8*)&Ks[t * 16 + lr][lq * 8];
            bf16x8 b1 = *(const bf16x8*)&Ks[t * 16 + lr][32 + lq * 8];
            f32x4 a = {};
            a = __builtin_amdgcn_mfma_f32_16x16x32_bf16(aq[0], b0, a, 0, 0, 0);
            a = __builtin_amdgcn_mfma_f32_16x16x32_bf16(aq[1], b1, a, 0, 0, 0);
            s[t] = a;
        }
        // position-based mask (uniform branch outside boundary region)
        if (kt < bs_blockmax) {
            #pragma unroll
            for (int t = 0; t < 4; t++) {
                const int col = kt + t * 16 + lr;
                #pragma unroll
                for (int r = 0; r < 4; r++)
                    if (col < bs_r[r]) s[t][r] = -1e9f;
            }
        }
        // p = exp2(s); accumulate denominator; write P band
        #pragma unroll
        for (int t = 0; t < 4; t++) {
            #pragma unroll
            for (int r = 0; r < 4; r++) {
                const float p = exp2f(s[t][r]);
                l_i[r] += p;
                Ps[wave * 16 + lq * 4 + r][t * 16 + lr] = (__bf16)p;
            }
        }
        // O += P V  (2 K-halves of 32 keys)
        #pragma unroll
        for (int ks2 = 0; ks2 < 2; ks2++) {
            bf16x8 ap = *(const bf16x8*)&Ps[wave * 16 + lr][ks2 * 32 + lq * 8];
            #pragma unroll
            for (int dt = 0; dt < 4; dt++) {
                bf16x8 bv = *(const bf16x8*)&Vs[dt * 16 + lr][ks2 * 32 + lq * 8];
                o[dt] = __builtin_amdgcn_mfma_f32_16x16x32_bf16(ap, bv, o[dt], 0, 0, 0);
            }
        }
    }

    // reduce denominator across the 16-lane row groups
    #pragma unroll
    for (int r = 0; r < 4; r++) {
        float v = l_i[r];
        v += __shfl_xor(v, 1);
        v += __shfl_xor(v, 2);
        v += __shfl_xor(v, 4);
        v += __shfl_xor(v, 8);
        l_i[r] = v;
    }
    // store partials
    float* pob = po + (((size_t)(ck * NHEAD + h) * N_TOK) + qbase) * HD;
    #pragma unroll
    for (int dt = 0; dt < 4; dt++)
        #pragma unroll
        for (int r = 0; r < 4; r++)
            pob[(lq * 4 + r) * HD + dt * 16 + lr] = o[dt][r];
    if (lr == 0) {
        #pragma unroll
        for (int r = 0; r < 4; r++)
            pl[(size_t)(ck * NHEAD + h) * N_TOK + qbase + lq * 4 + r] = l_i[r];
    }
}

// ---------------- combine split-K partials, normalize, scatter to ctx ----------------
__global__ __launch_bounds__(256) void combine_kernel(const float* __restrict__ po,
                                                      const float* __restrict__ pl,
                                                      const int* __restrict__ perm,
                                                      __bf16* __restrict__ ctx) {
    const int e = blockIdx.x * 256 + threadIdx.x;   // over 4096*512
    const int q = e >> 9;
    const int col = e & 511;
    const int h = col >> 6, d = col & 63;
    float s = 0.f, l = 0.f;
    #pragma unroll
    for (int c = 0; c < SPLITK; c++) {
        s += po[(((size_t)(c * NHEAD + h) * N_TOK) + q) * HD + d];
        l += pl[(size_t)(c * NHEAD + h) * N_TOK + q];
    }
    ctx[(size_t)perm[q] * EDIM + col] = (__bf16)(s / l);
}

// ---------------- embeddings: combined cols [512, 896) ----------------
__global__ void embed_kernel(const int* __restrict__ dmask, const int* __restrict__ steps,
                             const float* __restrict__ status, __bf16* __restrict__ combined) {
    const int n = blockIdx.x;
    const int c = threadIdx.x;               // 0..383
    __bf16 v;
    if (c < 128) {
        v = (__bf16)status[dmask[n] * 128 + c];
    } else {
        const int st = min(max(steps[n], 0), NBIN - 1);
        const int c2 = c - 128;
        const int p = c2 >> 1;
        const float div = expf((float)(2 * p) * (-9.210340371976184f / 256.0f));
        const float ang = (float)st * div;
        v = (__bf16)((c2 & 1) ? cosf(ang) : sinf(ang));
    }
    combined[(size_t)n * LDCOMB + EDIM + c] = v;
}

// ---------------- LayerNorm + ReLU + residual ----------------
__global__ __launch_bounds__(256) void ln_kernel(const float* __restrict__ h,
                                                 const float* __restrict__ x,
                                                 const float* __restrict__ gamma,
                                                 const float* __restrict__ beta,
                                                 float* __restrict__ out) {
    const int row = blockIdx.x * 4 + (threadIdx.x >> 6);
    const int lane = threadIdx.x & 63;
    const float* hr = h + (size_t)row * EDIM;
    float4 v0 = ((const float4*)hr)[lane];
    float4 v1 = ((const float4*)hr)[64 + lane];
    float sum = v0.x + v0.y + v0.z + v0.w + v1.x + v1.y + v1.z + v1.w;
    float sq = v0.x * v0.x + v0.y * v0.y + v0.z * v0.z + v0.w * v0.w +
               v1.x * v1.x + v1.y * v1.y + v1.z * v1.z + v1.w * v1.w;
    #pragma unroll
    for (int m = 1; m < 64; m <<= 1) {
        sum += __shfl_xor(sum, m);
        sq  += __shfl_xor(sq, m);
    }
    const float mean = sum * (1.0f / EDIM);
    const float var = sq * (1.0f / EDIM) - mean * mean;
    const float rstd = rsqrtf(var + 1e-5f);
    const float* xr = x + (size_t)row * EDIM;
    float* orow = out + (size_t)row * EDIM;
    #pragma unroll
    for (int half = 0; half < 2; half++) {
        const float4 v = half ? v1 : v0;
        const int cb = half * 256 + lane * 4;
        float4 res;
        const float* vp = (const float*)&v;
        float tmp[4];
        #pragma unroll
        for (int i = 0; i < 4; i++) {
            const int c = cb + i;
            float t = (vp[i] - mean) * rstd * gamma[c] + beta[c];
            t = fmaxf(t, 0.f);
            tmp[i] = xr[c] + t;
        }
        res.x = tmp[0]; res.y = tmp[1]; res.z = tmp[2]; res.w = tmp[3];
        ((float4*)orow)[cb >> 2] = res;
    }
}

// ---------------- launch ----------------
extern "C" void kernel_launch(void* const* d_in, const int* in_sizes, int n_in,
                              void* d_out, int out_size, void* d_ws, size_t ws_size,
                              hipStream_t stream) {
    const float* x      = (const float*)d_in[0];
    const int*   dmask  = (const int*)d_in[1];
    const int*   steps  = (const int*)d_in[2];
    const float* status = (const float*)d_in[3];
    const float* w_in   = (const float*)d_in[4];
    const float* b_in   = (const float*)d_in[5];
    const float* w_out  = (const float*)d_in[6];
    const float* b_out  = (const float*)d_in[7];
    const float* w_mlp  = (const float*)d_in[8];
    const float* b_mlp  = (const float*)d_in[9];
    const float* gamma  = (const float*)d_in[10];
    const float* beta   = (const float*)d_in[11];
    float* out = (float*)d_out;

    char* ws = (char*)d_ws;
    size_t off = 0;
    auto alloc = [&](size_t bytes) {
        void* p = ws + off;
        off = (off + bytes + 255) & ~(size_t)255;
        return p;
    };
    __bf16* x_bf    = (__bf16*)alloc((size_t)N_TOK * EDIM * 2);   // reused as qs after qkv GEMM
    __bf16* wqkv_bf = (__bf16*)alloc((size_t)3 * EDIM * EDIM * 2);
    __bf16* wout_bf = (__bf16*)alloc((size_t)EDIM * EDIM * 2);
    __bf16* wmlp_bf = (__bf16*)alloc((size_t)EDIM * LDCOMB * 2);
    __bf16* qkv_bf  = (__bf16*)alloc((size_t)N_TOK * LDQKV * 2);
    __bf16* ks_bf   = (__bf16*)alloc((size_t)N_TOK * EDIM * 2);
    __bf16* vt_bf   = (__bf16*)alloc((size_t)EDIM * N_TOK * 2);
    __bf16* ctx_bf  = (__bf16*)alloc((size_t)N_TOK * EDIM * 2);
    __bf16* comb_bf = (__bf16*)alloc((size_t)N_TOK * LDCOMB * 2);
    float*  h_f32   = (float*)alloc((size_t)N_TOK * EDIM * 4);
    int*    perm    = (int*)alloc(N_TOK * 4);
    int*    sstep   = (int*)alloc(N_TOK * 4);
    int*    binst   = (int*)alloc(NBIN * 4);
    float*  po      = (float*)alloc((size_t)SPLITK * NHEAD * N_TOK * HD * 4);
    float*  pl      = (float*)alloc((size_t)SPLITK * NHEAD * N_TOK * 4);
    __bf16* qs_bf   = x_bf;   // alias: x_bf dead after qkv GEMM

    // fused converts
    {
        const int n0 = N_TOK * EDIM / 4;
        const int n1 = 3 * EDIM * EDIM / 4;
        const int n2 = EDIM * EDIM / 4;
        const int n3 = EDIM * LDCOMB / 4;
        const int tot = n0 + n1 + n2 + n3;
        cvt4_kernel<<<(tot + 255) / 256, 256, 0, stream>>>(
            x, x_bf, n0, w_in, wqkv_bf, n1, w_out, wout_bf, n2, w_mlp, wmlp_bf, n3);
    }
    // qkv = x @ w_in^T + b_in
    gemm_nt<1><<<dim3(N_TOK / 128, 3 * EDIM / 128), 256, 0, stream>>>(
        x_bf, EDIM, wqkv_bf, EDIM, b_in, qkv_bf, LDQKV, EDIM);
    // counting sort by step
    sort_kernel<<<1, 1024, 0, stream>>>(steps, perm, sstep, binst);
    // gather sorted Q/K/V^T
    gather_kernel<<<dim3(N_TOK / 64, NHEAD), 256, 0, stream>>>(qkv_bf, perm, qs_bf, ks_bf, vt_bf);
    // attention (split-K, LDS-staged)
    attn_kernel<<<dim3(N_TOK / 64, NHEAD, SPLITK), 256, 0, stream>>>(
        qs_bf, ks_bf, vt_bf, sstep, binst, po, pl);
    // combine partials -> ctx (original token order)
    combine_kernel<<<(N_TOK * EDIM) / 256, 256, 0, stream>>>(po, pl, perm, ctx_bf);
    // out proj
    gemm_nt<1><<<dim3(N_TOK / 128, EDIM / 128), 256, 0, stream>>>(
        ctx_bf, EDIM, wout_bf, EDIM, b_out, comb_bf, LDCOMB, EDIM);
    // embeddings
    embed_kernel<<<N_TOK, 384, 0, stream>>>(dmask, steps, status, comb_bf);
    // mlp
    gemm_nt<0><<<dim3(N_TOK / 128, EDIM / 128), 256, 0, stream>>>(
        comb_bf, LDCOMB, wmlp_bf, LDCOMB, b_mlp, h_f32, EDIM, LDCOMB);
    // LN + ReLU + residual
    ln_kernel<<<N_TOK / 4, 256, 0, stream>>>(h_f32, x, gamma, beta, out);
}